// Round 17
// baseline (133.363 us; speedup 1.0000x reference)
//
#include <hip/hip_runtime.h>

// GCN: out[m,n,o] = (A_hat relu(A_hat (x W1) + b1) W_out[m])[n,o] + b_out[m,o]
// A_hat = D^-1/2 (A + I) D^-1/2.
// R17 = R16 + tail trims:
//  - csr as ushort (N<65536): halves csr write+read streams, csrsb LDS 20KB.
//  - gemm: persistent 256-block grid, W staged once per block (was 391x).
//  - prop1 untouched: 55us = L2-miss-tier floor (150MB @ ~2.8TB/s, 5x confirmed).
//  - prep/prop2: R16-proven forms.

constexpr int CIN = 128;
constexpr int SSHIFT = 8;        // 256 nodes per super-bucket
constexpr int NBLKB = 256;       // partition blocks == scan chunk size
constexpr int CSR_CAP = 10240;   // LDS sort capacity (mean ~8163, std ~90)

typedef __attribute__((ext_vector_type(8))) short short8v;
typedef __attribute__((ext_vector_type(4))) float float4v;

__device__ inline unsigned pack_bf16x2(float a, float b) {
  unsigned ua = __float_as_uint(a), ub = __float_as_uint(b);
  ua = (ua + 0x7FFFu + ((ua >> 16) & 1u)) >> 16;
  ub = (ub + 0x7FFFu + ((ub >> 16) & 1u)) >> 16;
  return ua | (ub << 16);
}
__device__ inline float bf_lo(unsigned u) { return __uint_as_float(u << 16); }
__device__ inline float bf_hi(unsigned u) { return __uint_as_float(u & 0xFFFF0000u); }
__device__ inline unsigned short round_bf16(float v) {
  unsigned ua = __float_as_uint(v);
  return (unsigned short)((ua + 0x7FFFu + ((ua >> 16) & 1u)) >> 16);
}

// ---------- pass A: per-block super-bucket histogram (int4 reads) ----------
__global__ __launch_bounds__(256) void histsb_k(const int* __restrict__ dst,
    int* __restrict__ blockhist, int E, int nsb) {
  __shared__ int lh[256];
  int b = blockIdx.x, t = threadIdx.x;
  lh[t] = 0;
  __syncthreads();
  int per = (((E + NBLKB - 1) / NBLKB) + 3) & ~3;
  int s0 = b * per, s1 = min(E, s0 + per);
  for (int i = s0 + 4 * t; i + 3 < s1; i += 1024) {
    int4 d4 = *(const int4*)&dst[i];
    atomicAdd(&lh[d4.x >> SSHIFT], 1);
    atomicAdd(&lh[d4.y >> SSHIFT], 1);
    atomicAdd(&lh[d4.z >> SSHIFT], 1);
    atomicAdd(&lh[d4.w >> SSHIFT], 1);
  }
  int tail0 = s0 + ((s1 - s0) & ~3);
  for (int i = tail0 + t; i < s1; i += 256) atomicAdd(&lh[dst[i] >> SSHIFT], 1);
  __syncthreads();
  if (t < nsb) blockhist[t * NBLKB + b] = lh[t];
}

// exclusive scan over NSC entries, 256/block; writes per-chunk totals
__global__ __launch_bounds__(256) void scan_k(const int* __restrict__ v_in,
    int* __restrict__ excl_out, int* __restrict__ btot, int n) {
  __shared__ int wsum[4];
  int t = threadIdx.x, l = t & 63, w = t >> 6;
  int i = blockIdx.x * 256 + t;
  int v = (i < n) ? v_in[i] : 0;
  int orig = v;
  #pragma unroll
  for (int off = 1; off < 64; off <<= 1) {
    int u = __shfl_up(v, off);
    if (l >= off) v += u;
  }
  if (l == 63) wsum[w] = v;
  __syncthreads();
  int add = 0;
  #pragma unroll
  for (int j = 0; j < 4; ++j) if (j < w) add += wsum[j];
  v += add;
  if (i < n) excl_out[i] = v - orig;
  if (t == 255) btot[blockIdx.x] = v;
}

// ---------- pass B: write edges to exact (block,super) ranges ----------
__global__ __launch_bounds__(256) void stageB_k(const int* __restrict__ src,
    const int* __restrict__ dst, const int* __restrict__ soff,
    const int* __restrict__ btot, unsigned* __restrict__ stage, int E, int nsb) {
  __shared__ int loff[256];
  __shared__ int wsum[4];
  int b = blockIdx.x, t = threadIdx.x, l = t & 63, w = t >> 6;
  int bv = (t < nsb) ? btot[t] : 0;
  int vv = bv;
  #pragma unroll
  for (int o = 1; o < 64; o <<= 1) { int u = __shfl_up(vv, o); if (l >= o) vv += u; }
  if (l == 63) wsum[w] = vv;
  __syncthreads();
  int add = 0;
  #pragma unroll
  for (int j = 0; j < 4; ++j) if (j < w) add += wsum[j];
  int bexcl = vv + add - bv;           // exclusive prefix of btot at t
  if (t < nsb) loff[t] = soff[t * NBLKB + b] + bexcl;
  __syncthreads();
  int per = (((E + NBLKB - 1) / NBLKB) + 3) & ~3;
  int s0 = b * per, s1 = min(E, s0 + per);
  for (int i = s0 + 4 * t; i + 3 < s1; i += 1024) {
    int4 d4 = *(const int4*)&dst[i];
    int4 s4 = *(const int4*)&src[i];
    int p0 = atomicAdd(&loff[d4.x >> SSHIFT], 1);
    stage[p0] = (unsigned)s4.x | ((unsigned)(d4.x & 255) << 17);
    int p1 = atomicAdd(&loff[d4.y >> SSHIFT], 1);
    stage[p1] = (unsigned)s4.y | ((unsigned)(d4.y & 255) << 17);
    int p2 = atomicAdd(&loff[d4.z >> SSHIFT], 1);
    stage[p2] = (unsigned)s4.z | ((unsigned)(d4.z & 255) << 17);
    int p3 = atomicAdd(&loff[d4.w >> SSHIFT], 1);
    stage[p3] = (unsigned)s4.w | ((unsigned)(d4.w & 255) << 17);
  }
  int tail0 = s0 + ((s1 - s0) & ~3);
  for (int i = tail0 + t; i < s1; i += 256) {
    int d = dst[i], s = src[i];
    int pos = atomicAdd(&loff[d >> SSHIFT], 1);
    stage[pos] = (unsigned)s | ((unsigned)(d & 255) << 17);
  }
}

// ---------- per-super LDS count-sort: stage -> per-node CSR(u16) + dinv ----------
__global__ __launch_bounds__(256) void csrsb_k(const unsigned* __restrict__ stage,
    const int* __restrict__ btot, int* __restrict__ row_ptr,
    unsigned short* __restrict__ csr, float* __restrict__ dinv,
    int N, int E, int nsb) {
  __shared__ int cnt[256], off[256], cur[256], sboff[256];
  __shared__ unsigned ebuf[CSR_CAP];
  __shared__ unsigned short sbuf[CSR_CAP];
  __shared__ int wsum[4];
  int k = blockIdx.x, t = threadIdx.x, l = t & 63, w = t >> 6;
  cnt[t] = 0; cur[t] = 0;
  {
    int bv = (t < nsb) ? btot[t] : 0;
    int vv = bv;
    #pragma unroll
    for (int o = 1; o < 64; o <<= 1) { int u = __shfl_up(vv, o); if (l >= o) vv += u; }
    if (l == 63) wsum[w] = vv;
    __syncthreads();
    int add = 0;
    #pragma unroll
    for (int j = 0; j < 4; ++j) if (j < w) add += wsum[j];
    sboff[t] = vv + add - bv;
  }
  __syncthreads();
  int r0 = sboff[k];
  int r1 = (k + 1 < nsb) ? sboff[k + 1] : E;
  int len = r1 - r0;
  bool fits = len <= CSR_CAP;
  if (fits) {
    for (int i = t; i < len; i += 256) {
      unsigned s = stage[r0 + i];
      ebuf[i] = s;
      atomicAdd(&cnt[s >> 17], 1);
    }
  } else {
    for (int i = r0 + t; i < r1; i += 256) atomicAdd(&cnt[stage[i] >> 17], 1);
  }
  __syncthreads();
  {
    int v = cnt[t], orig = v;
    #pragma unroll
    for (int o = 1; o < 64; o <<= 1) {
      int u = __shfl_up(v, o);
      if (l >= o) v += u;
    }
    if (l == 63) wsum[w] = v;
    __syncthreads();
    int add = 0;
    #pragma unroll
    for (int j = 0; j < 4; ++j) if (j < w) add += wsum[j];
    int excl = v + add - orig;
    off[t] = excl;
    int n = (k << SSHIFT) + t;
    if (n < N) {
      row_ptr[n] = r0 + excl;
      dinv[n] = rsqrtf((float)(orig + 1));
    }
    if (k == nsb - 1 && t == 255) row_ptr[N] = E;
  }
  __syncthreads();
  if (fits) {
    for (int i = t; i < len; i += 256) {
      unsigned s = ebuf[i];
      int dl = s >> 17;
      int pos = off[dl] + atomicAdd(&cur[dl], 1);
      sbuf[pos] = (unsigned short)(s & 0xFFFF);
    }
    __syncthreads();
    for (int i = t; i < len; i += 256) csr[r0 + i] = sbuf[i];
  } else {
    for (int i = r0 + t; i < r1; i += 256) {
      unsigned s = stage[i];
      int dl = s >> 17;
      int pos = r0 + off[dl] + atomicAdd(&cur[dl], 1);
      csr[pos] = (unsigned short)(s & 0xFFFF);
    }
  }
}

// ---------- g(bf16, row-major) = dinv[n]*(x@W1), pure-bf16 MFMA ----------
// persistent 256-block grid: W staged once per block, row-tiles grid-stride.
__global__ __launch_bounds__(256) void gemm_k(const float* __restrict__ x,
    const float* __restrict__ W, const float* __restrict__ dinv,
    unsigned* __restrict__ gu, int nrows) {
  __shared__ unsigned short Bh[16384];   // W bf16  [kstep][coltile][lane][j]
  __shared__ unsigned short Ah[4096];    // x bf16  [kg][row][j]  (one k-step)
  int t = threadIdx.x, l = t & 63, w = t >> 6;
  for (int idx = t; idx < 16384; idx += 256) {
    int k = idx >> 7, col = idx & 127;
    int addr = (((k >> 5) * 8 + (col >> 4)) * 64 +
                (((k >> 3) & 3) * 16 + (col & 15))) * 8 + (k & 7);
    Bh[addr] = round_bf16(W[idx]);
  }

  int ct0 = w * 2;                       // wave's two col-tiles
  int arow = l & 15;
  int kg = l >> 4;
  int srow = t >> 1, skh = t & 1;        // staging: thread -> (row, k-half)
  int ntiles = (nrows + 127) >> 7;

  for (int tile = blockIdx.x; tile < ntiles; tile += gridDim.x) {
    int row0 = tile << 7;
    int sgrow = min(row0 + srow, nrows - 1);
    float4v acc[8][2];
    #pragma unroll
    for (int i = 0; i < 8; ++i) { acc[i][0] = (float4v)0.f; acc[i][1] = (float4v)0.f; }

    for (int ks = 0; ks < 4; ++ks) {
      __syncthreads();
      {                                  // round this k-step's x-tile to bf16
        const float* xp = &x[(size_t)sgrow * CIN + ks * 32 + skh * 16];
        float f[16];
        *(float4*)&f[0]  = *(const float4*)xp;
        *(float4*)&f[4]  = *(const float4*)(xp + 4);
        *(float4*)&f[8]  = *(const float4*)(xp + 8);
        *(float4*)&f[12] = *(const float4*)(xp + 12);
        #pragma unroll
        for (int h = 0; h < 2; ++h) {
          short8v ah_;
          #pragma unroll
          for (int j = 0; j < 8; ++j) ah_[j] = (short)round_bf16(f[h * 8 + j]);
          int g = skh * 2 + h;
          *(short8v*)&Ah[(g * 128 + srow) * 8] = ah_;
        }
      }
      __syncthreads();
      short8v bh0 = *(short8v*)&Bh[((ks * 8 + ct0) * 64 + l) * 8];
      short8v bh1 = *(short8v*)&Bh[((ks * 8 + ct0 + 1) * 64 + l) * 8];
      #pragma unroll
      for (int rt = 0; rt < 8; ++rt) {
        int ar = arow + rt * 16;
        short8v ah = *(short8v*)&Ah[(kg * 128 + ar) * 8];
        acc[rt][0] = __builtin_amdgcn_mfma_f32_16x16x32_bf16(ah, bh0, acc[rt][0], 0, 0, 0);
        acc[rt][1] = __builtin_amdgcn_mfma_f32_16x16x32_bf16(ah, bh1, acc[rt][1], 0, 0, 0);
      }
    }
    // epilogue: D col = l&15, row = 4*(l>>4)+reg [HW-verified]; row-major gu
    #pragma unroll
    for (int rt = 0; rt < 8; ++rt) {
      #pragma unroll
      for (int r = 0; r < 4; ++r) {
        int row = row0 + rt * 16 + (l >> 4) * 4 + r;
        bool ok = row < nrows;
        float dv = ok ? dinv[row] : 0.f;
        #pragma unroll
        for (int c = 0; c < 2; ++c) {
          float val = acc[rt][c][r] * dv;
          float other = __shfl_xor(val, 1);
          int col = (ct0 + c) * 16 + (l & 15);
          if (ok && !(l & 1)) gu[(size_t)row * 64 + (col >> 1)] = pack_bf16x2(val, other);
        }
      }
    }
  }
}

// ---------- propagate-1: 16-lane x uint4 row gather + fused epilogue ----------
#define ACC8(U) do { \
  acc[0] += bf_lo((U).x); acc[1] += bf_hi((U).x); \
  acc[2] += bf_lo((U).y); acc[3] += bf_hi((U).y); \
  acc[4] += bf_lo((U).z); acc[5] += bf_hi((U).z); \
  acc[6] += bf_lo((U).w); acc[7] += bf_hi((U).w); } while (0)

__global__ __launch_bounds__(256) void prop1_k(const uint4* __restrict__ g4,
    const int* __restrict__ row_ptr, const unsigned short* __restrict__ csr,
    const float* __restrict__ dinv, const float* __restrict__ b1,
    const float* __restrict__ Wout, unsigned* __restrict__ g2w,
    int n_nodes, int n_waves) {
  int l = threadIdx.x & 63;
  int q = l & 15, sub = l >> 4;     // lane q covers cols 8q..8q+7; sub owns j=2sub,2sub+1
  int wid = (blockIdx.x * blockDim.x + threadIdx.x) >> 6;
  float wj0[8], wj1[8], bb[8];
  #pragma unroll
  for (int c = 0; c < 8; ++c) {
    int col = 8 * q + c;
    wj0[c] = Wout[sub * 256 + col * 2];
    wj1[c] = Wout[sub * 256 + col * 2 + 1];
    bb[c] = b1[col];
  }
  for (int n = wid; n < n_nodes; n += n_waves) {
    int start = row_ptr[n], end = row_ptr[n + 1];
    float d = dinv[n];
    float acc[8];
    #pragma unroll
    for (int c = 0; c < 8; ++c) acc[c] = 0.f;
    for (int base = start; base < end; base += 64) {
      int cnt = min(64, end - base);
      int eb = (base + l < end) ? (int)csr[base + l] : 0;
      int i = 0;
      for (; i + 16 <= cnt; i += 16) {
        int s0 = __shfl(eb, i + sub);
        int s1 = __shfl(eb, i + 4 + sub);
        int s2 = __shfl(eb, i + 8 + sub);
        int s3 = __shfl(eb, i + 12 + sub);
        uint4 u0 = g4[s0 * 16 + q];
        uint4 u1 = g4[s1 * 16 + q];
        uint4 u2 = g4[s2 * 16 + q];
        uint4 u3 = g4[s3 * 16 + q];
        ACC8(u0); ACC8(u1); ACC8(u2); ACC8(u3);
      }
      for (; i + 4 <= cnt; i += 4) {
        int s0 = __shfl(eb, i + sub);
        uint4 u0 = g4[s0 * 16 + q];
        ACC8(u0);
      }
      if (i < cnt) {
        int idx = i + sub;
        bool vld = idx < cnt;
        int s0 = __shfl(eb, vld ? idx : i);
        uint4 u0 = g4[s0 * 16 + q];
        if (vld) { ACC8(u0); }
      }
    }
    #pragma unroll
    for (int c = 0; c < 8; ++c) {   // merge the 4 sub-waves
      acc[c] += __shfl_xor(acc[c], 16);
      acc[c] += __shfl_xor(acc[c], 32);
    }
    uint4 us = g4[n * 16 + q];       // self-loop (dinv folded in g)
    ACC8(us);
    float p0 = 0.f, p1 = 0.f;
    #pragma unroll
    for (int c = 0; c < 8; ++c) {
      float y = fmaxf(fmaf(acc[c], d, bb[c]), 0.f);
      p0 = fmaf(y, wj0[c], p0);
      p1 = fmaf(y, wj1[c], p1);
    }
    #pragma unroll
    for (int off = 1; off < 16; off <<= 1) {
      p0 += __shfl_xor(p0, off);
      p1 += __shfl_xor(p1, off);
    }
    if (q == 0) g2w[n * 4 + sub] = pack_bf16x2(d * p0, d * p1);
  }
}

// ---------- propagate-2: 4 threads/node (edge-split pairs), 8-deep ILP ----------
__global__ __launch_bounds__(256) void prop2_k(const uint2* __restrict__ g2v,
    const int* __restrict__ row_ptr, const unsigned short* __restrict__ csr,
    const float* __restrict__ dinv, const float* __restrict__ bout,
    float* __restrict__ out, int N) {
  int tid = blockIdx.x * 256 + threadIdx.x;
  int n = tid >> 2;
  if (n >= N) return;
  int hf = tid & 1, part = (tid >> 1) & 1;
  int start = row_ptr[n], end = row_ptr[n + 1];
  int mid = start + ((end - start) >> 1);
  int e  = part ? mid : start;
  int e1 = part ? end : mid;
  float a0 = 0.f, a1 = 0.f, a2 = 0.f, a3 = 0.f;
  if (!part) {
    uint2 us = g2v[n * 2 + hf];     // self-loop
    a0 = bf_lo(us.x); a1 = bf_hi(us.x);
    a2 = bf_lo(us.y); a3 = bf_hi(us.y);
  }
  for (; e + 8 <= e1; e += 8) {
    int i0 = csr[e],     i1 = csr[e + 1], i2 = csr[e + 2], i3 = csr[e + 3];
    int i4 = csr[e + 4], i5 = csr[e + 5], i6 = csr[e + 6], i7 = csr[e + 7];
    uint2 u0 = g2v[i0 * 2 + hf], u1 = g2v[i1 * 2 + hf];
    uint2 u2 = g2v[i2 * 2 + hf], u3 = g2v[i3 * 2 + hf];
    uint2 u4 = g2v[i4 * 2 + hf], u5 = g2v[i5 * 2 + hf];
    uint2 u6 = g2v[i6 * 2 + hf], u7 = g2v[i7 * 2 + hf];
    a0 += ((bf_lo(u0.x) + bf_lo(u1.x)) + (bf_lo(u2.x) + bf_lo(u3.x)))
        + ((bf_lo(u4.x) + bf_lo(u5.x)) + (bf_lo(u6.x) + bf_lo(u7.x)));
    a1 += ((bf_hi(u0.x) + bf_hi(u1.x)) + (bf_hi(u2.x) + bf_hi(u3.x)))
        + ((bf_hi(u4.x) + bf_hi(u5.x)) + (bf_hi(u6.x) + bf_hi(u7.x)));
    a2 += ((bf_lo(u0.y) + bf_lo(u1.y)) + (bf_lo(u2.y) + bf_lo(u3.y)))
        + ((bf_lo(u4.y) + bf_lo(u5.y)) + (bf_lo(u6.y) + bf_lo(u7.y)));
    a3 += ((bf_hi(u0.y) + bf_hi(u1.y)) + (bf_hi(u2.y) + bf_hi(u3.y)))
        + ((bf_hi(u4.y) + bf_hi(u5.y)) + (bf_hi(u6.y) + bf_hi(u7.y)));
  }
  for (; e + 4 <= e1; e += 4) {
    int i0 = csr[e], i1 = csr[e + 1], i2 = csr[e + 2], i3 = csr[e + 3];
    uint2 u0 = g2v[i0 * 2 + hf], u1 = g2v[i1 * 2 + hf];
    uint2 u2 = g2v[i2 * 2 + hf], u3 = g2v[i3 * 2 + hf];
    a0 += (bf_lo(u0.x) + bf_lo(u1.x)) + (bf_lo(u2.x) + bf_lo(u3.x));
    a1 += (bf_hi(u0.x) + bf_hi(u1.x)) + (bf_hi(u2.x) + bf_hi(u3.x));
    a2 += (bf_lo(u0.y) + bf_lo(u1.y)) + (bf_lo(u2.y) + bf_lo(u3.y));
    a3 += (bf_hi(u0.y) + bf_hi(u1.y)) + (bf_hi(u2.y) + bf_hi(u3.y));
  }
  for (; e < e1; ++e) {
    uint2 u = g2v[csr[e] * 2 + hf];
    a0 += bf_lo(u.x); a1 += bf_hi(u.x);
    a2 += bf_lo(u.y); a3 += bf_hi(u.y);
  }
  // combine the two edge-halves (partner thread = tid^2, same wave)
  a0 += __shfl_xor(a0, 2);
  a1 += __shfl_xor(a1, 2);
  a2 += __shfl_xor(a2, 2);
  a3 += __shfl_xor(a3, 2);
  if (!part) {
    float d = dinv[n];
    float2 o0 = make_float2(fmaf(d, a0, bout[hf * 4 + 0]), fmaf(d, a1, bout[hf * 4 + 1]));
    float2 o1 = make_float2(fmaf(d, a2, bout[hf * 4 + 2]), fmaf(d, a3, bout[hf * 4 + 3]));
    *(float2*)&out[(size_t)(hf * 2 + 0) * (2 * N) + 2 * n] = o0;
    *(float2*)&out[(size_t)(hf * 2 + 1) * (2 * N) + 2 * n] = o1;
  }
}

extern "C" void kernel_launch(void* const* d_in, const int* in_sizes, int n_in,
                              void* d_out, int out_size, void* d_ws, size_t ws_size,
                              hipStream_t stream) {
  const float* x    = (const float*)d_in[0];
  const int*   ei   = (const int*)d_in[1];
  const float* W1   = (const float*)d_in[2];
  const float* b1   = (const float*)d_in[3];
  const float* Wout = (const float*)d_in[4];
  const float* bout = (const float*)d_in[5];
  float* out = (float*)d_out;

  const int N = in_sizes[0] / CIN;       // 50000
  const int E = in_sizes[1] / 2;         // 1600000
  const int* srcp = ei;
  const int* dstp = ei + E;
  const int NSB = (N + 255) >> SSHIFT;   // 196 super-buckets
  const int NSC = NSB * NBLKB;           // 50176 scan entries

  char* ws = (char*)d_ws;
  size_t off = 0;
  auto alloc = [&](size_t bytes) -> void* {
    void* p = ws + off;
    off = (off + bytes + 511) & ~(size_t)511;
    return p;
  };
  unsigned*       gu        = (unsigned*)alloc((size_t)N * 64 * 4);      // bf16 g, row-major
  unsigned short* g2u       = (unsigned short*)alloc((size_t)N * 8 * 2); // bf16 g2
  float*          dinv      = (float*)alloc((size_t)N * 4);
  int*            blockhist = (int*)alloc((size_t)NSC * 4);
  int*            soff      = (int*)alloc((size_t)NSC * 4);
  int*            btot      = (int*)alloc(256 * 4);
  int*            row_ptr   = (int*)alloc((size_t)(N + 1) * 4);
  unsigned short* csr       = (unsigned short*)alloc((size_t)E * 2);
  unsigned*       stage     = (unsigned*)alloc((size_t)E * 4);
  (void)ws_size; (void)n_in; (void)out_size;

  histsb_k<<<NBLKB, 256, 0, stream>>>(dstp, blockhist, E, NSB);
  scan_k<<<NSB, 256, 0, stream>>>(blockhist, soff, btot, NSC);
  stageB_k<<<NBLKB, 256, 0, stream>>>(srcp, dstp, soff, btot, stage, E, NSB);
  csrsb_k<<<NSB, 256, 0, stream>>>(stage, btot, row_ptr, csr, dinv, N, E, NSB);

  gemm_k<<<256, 256, 0, stream>>>(x, W1, dinv, gu, N);

  const int P1_BLOCKS = 2048;
  prop1_k<<<P1_BLOCKS, 256, 0, stream>>>((const uint4*)gu, row_ptr, csr, dinv, b1,
                                         Wout, (unsigned*)g2u, N, P1_BLOCKS * 4);
  prop2_k<<<(4 * N + 255) / 256, 256, 0, stream>>>((const uint2*)g2u, row_ptr, csr,
                                                   dinv, bout, out, N);
}

// Round 18
// 124.932 us; speedup vs baseline: 1.0675x; 1.0675x over previous
//
#include <hip/hip_runtime.h>

// GCN: out[m,n,o] = (A_hat relu(A_hat (x W1) + b1) W_out[m])[n,o] + b_out[m,o]
// A_hat = D^-1/2 (A + I) D^-1/2.
// R18 = R16 + u16 csr only (A/B isolating R17's regression):
//  - csr as ushort (N<65536): halves csr streams (prop1 FETCH 149.8->147.7MB,
//    measured R17), csrsb LDS 20KB.
//  - gemm: R16 per-tile 391-block launch (R17's persistent 256-block grid cost
//    ~7us: 1 block/CU occupancy + 2-tile tail imbalance).
//  - prop1 untouched: 55us = L2-miss-tier floor (150MB @ ~2.8TB/s, 6x confirmed).
//  - prep/prop2: R16-proven forms.

constexpr int CIN = 128;
constexpr int SSHIFT = 8;        // 256 nodes per super-bucket
constexpr int NBLKB = 256;       // partition blocks == scan chunk size
constexpr int CSR_CAP = 10240;   // LDS sort capacity (mean ~8163, std ~90)

typedef __attribute__((ext_vector_type(8))) short short8v;
typedef __attribute__((ext_vector_type(4))) float float4v;

__device__ inline unsigned pack_bf16x2(float a, float b) {
  unsigned ua = __float_as_uint(a), ub = __float_as_uint(b);
  ua = (ua + 0x7FFFu + ((ua >> 16) & 1u)) >> 16;
  ub = (ub + 0x7FFFu + ((ub >> 16) & 1u)) >> 16;
  return ua | (ub << 16);
}
__device__ inline float bf_lo(unsigned u) { return __uint_as_float(u << 16); }
__device__ inline float bf_hi(unsigned u) { return __uint_as_float(u & 0xFFFF0000u); }
__device__ inline unsigned short round_bf16(float v) {
  unsigned ua = __float_as_uint(v);
  return (unsigned short)((ua + 0x7FFFu + ((ua >> 16) & 1u)) >> 16);
}

// ---------- pass A: per-block super-bucket histogram (int4 reads) ----------
__global__ __launch_bounds__(256) void histsb_k(const int* __restrict__ dst,
    int* __restrict__ blockhist, int E, int nsb) {
  __shared__ int lh[256];
  int b = blockIdx.x, t = threadIdx.x;
  lh[t] = 0;
  __syncthreads();
  int per = (((E + NBLKB - 1) / NBLKB) + 3) & ~3;
  int s0 = b * per, s1 = min(E, s0 + per);
  for (int i = s0 + 4 * t; i + 3 < s1; i += 1024) {
    int4 d4 = *(const int4*)&dst[i];
    atomicAdd(&lh[d4.x >> SSHIFT], 1);
    atomicAdd(&lh[d4.y >> SSHIFT], 1);
    atomicAdd(&lh[d4.z >> SSHIFT], 1);
    atomicAdd(&lh[d4.w >> SSHIFT], 1);
  }
  int tail0 = s0 + ((s1 - s0) & ~3);
  for (int i = tail0 + t; i < s1; i += 256) atomicAdd(&lh[dst[i] >> SSHIFT], 1);
  __syncthreads();
  if (t < nsb) blockhist[t * NBLKB + b] = lh[t];
}

// exclusive scan over NSC entries, 256/block; writes per-chunk totals
__global__ __launch_bounds__(256) void scan_k(const int* __restrict__ v_in,
    int* __restrict__ excl_out, int* __restrict__ btot, int n) {
  __shared__ int wsum[4];
  int t = threadIdx.x, l = t & 63, w = t >> 6;
  int i = blockIdx.x * 256 + t;
  int v = (i < n) ? v_in[i] : 0;
  int orig = v;
  #pragma unroll
  for (int off = 1; off < 64; off <<= 1) {
    int u = __shfl_up(v, off);
    if (l >= off) v += u;
  }
  if (l == 63) wsum[w] = v;
  __syncthreads();
  int add = 0;
  #pragma unroll
  for (int j = 0; j < 4; ++j) if (j < w) add += wsum[j];
  v += add;
  if (i < n) excl_out[i] = v - orig;
  if (t == 255) btot[blockIdx.x] = v;
}

// ---------- pass B: write edges to exact (block,super) ranges ----------
__global__ __launch_bounds__(256) void stageB_k(const int* __restrict__ src,
    const int* __restrict__ dst, const int* __restrict__ soff,
    const int* __restrict__ btot, unsigned* __restrict__ stage, int E, int nsb) {
  __shared__ int loff[256];
  __shared__ int wsum[4];
  int b = blockIdx.x, t = threadIdx.x, l = t & 63, w = t >> 6;
  int bv = (t < nsb) ? btot[t] : 0;
  int vv = bv;
  #pragma unroll
  for (int o = 1; o < 64; o <<= 1) { int u = __shfl_up(vv, o); if (l >= o) vv += u; }
  if (l == 63) wsum[w] = vv;
  __syncthreads();
  int add = 0;
  #pragma unroll
  for (int j = 0; j < 4; ++j) if (j < w) add += wsum[j];
  int bexcl = vv + add - bv;           // exclusive prefix of btot at t
  if (t < nsb) loff[t] = soff[t * NBLKB + b] + bexcl;
  __syncthreads();
  int per = (((E + NBLKB - 1) / NBLKB) + 3) & ~3;
  int s0 = b * per, s1 = min(E, s0 + per);
  for (int i = s0 + 4 * t; i + 3 < s1; i += 1024) {
    int4 d4 = *(const int4*)&dst[i];
    int4 s4 = *(const int4*)&src[i];
    int p0 = atomicAdd(&loff[d4.x >> SSHIFT], 1);
    stage[p0] = (unsigned)s4.x | ((unsigned)(d4.x & 255) << 17);
    int p1 = atomicAdd(&loff[d4.y >> SSHIFT], 1);
    stage[p1] = (unsigned)s4.y | ((unsigned)(d4.y & 255) << 17);
    int p2 = atomicAdd(&loff[d4.z >> SSHIFT], 1);
    stage[p2] = (unsigned)s4.z | ((unsigned)(d4.z & 255) << 17);
    int p3 = atomicAdd(&loff[d4.w >> SSHIFT], 1);
    stage[p3] = (unsigned)s4.w | ((unsigned)(d4.w & 255) << 17);
  }
  int tail0 = s0 + ((s1 - s0) & ~3);
  for (int i = tail0 + t; i < s1; i += 256) {
    int d = dst[i], s = src[i];
    int pos = atomicAdd(&loff[d >> SSHIFT], 1);
    stage[pos] = (unsigned)s | ((unsigned)(d & 255) << 17);
  }
}

// ---------- per-super LDS count-sort: stage -> per-node CSR(u16) + dinv ----------
__global__ __launch_bounds__(256) void csrsb_k(const unsigned* __restrict__ stage,
    const int* __restrict__ btot, int* __restrict__ row_ptr,
    unsigned short* __restrict__ csr, float* __restrict__ dinv,
    int N, int E, int nsb) {
  __shared__ int cnt[256], off[256], cur[256], sboff[256];
  __shared__ unsigned ebuf[CSR_CAP];
  __shared__ unsigned short sbuf[CSR_CAP];
  __shared__ int wsum[4];
  int k = blockIdx.x, t = threadIdx.x, l = t & 63, w = t >> 6;
  cnt[t] = 0; cur[t] = 0;
  {
    int bv = (t < nsb) ? btot[t] : 0;
    int vv = bv;
    #pragma unroll
    for (int o = 1; o < 64; o <<= 1) { int u = __shfl_up(vv, o); if (l >= o) vv += u; }
    if (l == 63) wsum[w] = vv;
    __syncthreads();
    int add = 0;
    #pragma unroll
    for (int j = 0; j < 4; ++j) if (j < w) add += wsum[j];
    sboff[t] = vv + add - bv;
  }
  __syncthreads();
  int r0 = sboff[k];
  int r1 = (k + 1 < nsb) ? sboff[k + 1] : E;
  int len = r1 - r0;
  bool fits = len <= CSR_CAP;
  if (fits) {
    for (int i = t; i < len; i += 256) {
      unsigned s = stage[r0 + i];
      ebuf[i] = s;
      atomicAdd(&cnt[s >> 17], 1);
    }
  } else {
    for (int i = r0 + t; i < r1; i += 256) atomicAdd(&cnt[stage[i] >> 17], 1);
  }
  __syncthreads();
  {
    int v = cnt[t], orig = v;
    #pragma unroll
    for (int o = 1; o < 64; o <<= 1) {
      int u = __shfl_up(v, o);
      if (l >= o) v += u;
    }
    if (l == 63) wsum[w] = v;
    __syncthreads();
    int add = 0;
    #pragma unroll
    for (int j = 0; j < 4; ++j) if (j < w) add += wsum[j];
    int excl = v + add - orig;
    off[t] = excl;
    int n = (k << SSHIFT) + t;
    if (n < N) {
      row_ptr[n] = r0 + excl;
      dinv[n] = rsqrtf((float)(orig + 1));
    }
    if (k == nsb - 1 && t == 255) row_ptr[N] = E;
  }
  __syncthreads();
  if (fits) {
    for (int i = t; i < len; i += 256) {
      unsigned s = ebuf[i];
      int dl = s >> 17;
      int pos = off[dl] + atomicAdd(&cur[dl], 1);
      sbuf[pos] = (unsigned short)(s & 0xFFFF);
    }
    __syncthreads();
    for (int i = t; i < len; i += 256) csr[r0 + i] = sbuf[i];
  } else {
    for (int i = r0 + t; i < r1; i += 256) {
      unsigned s = stage[i];
      int dl = s >> 17;
      int pos = r0 + off[dl] + atomicAdd(&cur[dl], 1);
      csr[pos] = (unsigned short)(s & 0xFFFF);
    }
  }
}

// ---------- g(bf16, row-major) = dinv[n]*(x@W1), pure-bf16 MFMA ----------
__global__ __launch_bounds__(256) void gemm_k(const float* __restrict__ x,
    const float* __restrict__ W, const float* __restrict__ dinv,
    unsigned* __restrict__ gu, int nrows) {
  __shared__ unsigned short Bh[16384];   // W bf16  [kstep][coltile][lane][j]
  __shared__ unsigned short Ah[4096];    // x bf16  [kg][row][j]  (one k-step)
  int t = threadIdx.x, l = t & 63, w = t >> 6;
  for (int idx = t; idx < 16384; idx += 256) {
    int k = idx >> 7, col = idx & 127;
    int addr = (((k >> 5) * 8 + (col >> 4)) * 64 +
                (((k >> 3) & 3) * 16 + (col & 15))) * 8 + (k & 7);
    Bh[addr] = round_bf16(W[idx]);
  }

  int row0 = blockIdx.x * 128;
  int ct0 = w * 2;                       // wave's two col-tiles
  float4v acc[8][2];
  #pragma unroll
  for (int i = 0; i < 8; ++i) { acc[i][0] = (float4v)0.f; acc[i][1] = (float4v)0.f; }
  int arow = l & 15;
  int kg = l >> 4;
  int srow = t >> 1, skh = t & 1;        // staging: thread -> (row, k-half)
  int sgrow = min(row0 + srow, nrows - 1);

  for (int ks = 0; ks < 4; ++ks) {
    __syncthreads();
    {                                    // round this k-step's x-tile to bf16
      const float* xp = &x[(size_t)sgrow * CIN + ks * 32 + skh * 16];
      float f[16];
      *(float4*)&f[0]  = *(const float4*)xp;
      *(float4*)&f[4]  = *(const float4*)(xp + 4);
      *(float4*)&f[8]  = *(const float4*)(xp + 8);
      *(float4*)&f[12] = *(const float4*)(xp + 12);
      #pragma unroll
      for (int h = 0; h < 2; ++h) {
        short8v ah_;
        #pragma unroll
        for (int j = 0; j < 8; ++j) ah_[j] = (short)round_bf16(f[h * 8 + j]);
        int g = skh * 2 + h;
        *(short8v*)&Ah[(g * 128 + srow) * 8] = ah_;
      }
    }
    __syncthreads();
    short8v bh0 = *(short8v*)&Bh[((ks * 8 + ct0) * 64 + l) * 8];
    short8v bh1 = *(short8v*)&Bh[((ks * 8 + ct0 + 1) * 64 + l) * 8];
    #pragma unroll
    for (int rt = 0; rt < 8; ++rt) {
      int ar = arow + rt * 16;
      short8v ah = *(short8v*)&Ah[(kg * 128 + ar) * 8];
      acc[rt][0] = __builtin_amdgcn_mfma_f32_16x16x32_bf16(ah, bh0, acc[rt][0], 0, 0, 0);
      acc[rt][1] = __builtin_amdgcn_mfma_f32_16x16x32_bf16(ah, bh1, acc[rt][1], 0, 0, 0);
    }
  }
  // epilogue: D col = l&15, row = 4*(l>>4)+reg [HW-verified]; row-major gu
  #pragma unroll
  for (int rt = 0; rt < 8; ++rt) {
    #pragma unroll
    for (int r = 0; r < 4; ++r) {
      int row = row0 + rt * 16 + (l >> 4) * 4 + r;
      bool ok = row < nrows;
      float dv = ok ? dinv[row] : 0.f;
      #pragma unroll
      for (int c = 0; c < 2; ++c) {
        float val = acc[rt][c][r] * dv;
        float other = __shfl_xor(val, 1);
        int col = (ct0 + c) * 16 + (l & 15);
        if (ok && !(l & 1)) gu[(size_t)row * 64 + (col >> 1)] = pack_bf16x2(val, other);
      }
    }
  }
}

// ---------- propagate-1: 16-lane x uint4 row gather + fused epilogue ----------
#define ACC8(U) do { \
  acc[0] += bf_lo((U).x); acc[1] += bf_hi((U).x); \
  acc[2] += bf_lo((U).y); acc[3] += bf_hi((U).y); \
  acc[4] += bf_lo((U).z); acc[5] += bf_hi((U).z); \
  acc[6] += bf_lo((U).w); acc[7] += bf_hi((U).w); } while (0)

__global__ __launch_bounds__(256) void prop1_k(const uint4* __restrict__ g4,
    const int* __restrict__ row_ptr, const unsigned short* __restrict__ csr,
    const float* __restrict__ dinv, const float* __restrict__ b1,
    const float* __restrict__ Wout, unsigned* __restrict__ g2w,
    int n_nodes, int n_waves) {
  int l = threadIdx.x & 63;
  int q = l & 15, sub = l >> 4;     // lane q covers cols 8q..8q+7; sub owns j=2sub,2sub+1
  int wid = (blockIdx.x * blockDim.x + threadIdx.x) >> 6;
  float wj0[8], wj1[8], bb[8];
  #pragma unroll
  for (int c = 0; c < 8; ++c) {
    int col = 8 * q + c;
    wj0[c] = Wout[sub * 256 + col * 2];
    wj1[c] = Wout[sub * 256 + col * 2 + 1];
    bb[c] = b1[col];
  }
  for (int n = wid; n < n_nodes; n += n_waves) {
    int start = row_ptr[n], end = row_ptr[n + 1];
    float d = dinv[n];
    float acc[8];
    #pragma unroll
    for (int c = 0; c < 8; ++c) acc[c] = 0.f;
    for (int base = start; base < end; base += 64) {
      int cnt = min(64, end - base);
      int eb = (base + l < end) ? (int)csr[base + l] : 0;
      int i = 0;
      for (; i + 16 <= cnt; i += 16) {
        int s0 = __shfl(eb, i + sub);
        int s1 = __shfl(eb, i + 4 + sub);
        int s2 = __shfl(eb, i + 8 + sub);
        int s3 = __shfl(eb, i + 12 + sub);
        uint4 u0 = g4[s0 * 16 + q];
        uint4 u1 = g4[s1 * 16 + q];
        uint4 u2 = g4[s2 * 16 + q];
        uint4 u3 = g4[s3 * 16 + q];
        ACC8(u0); ACC8(u1); ACC8(u2); ACC8(u3);
      }
      for (; i + 4 <= cnt; i += 4) {
        int s0 = __shfl(eb, i + sub);
        uint4 u0 = g4[s0 * 16 + q];
        ACC8(u0);
      }
      if (i < cnt) {
        int idx = i + sub;
        bool vld = idx < cnt;
        int s0 = __shfl(eb, vld ? idx : i);
        uint4 u0 = g4[s0 * 16 + q];
        if (vld) { ACC8(u0); }
      }
    }
    #pragma unroll
    for (int c = 0; c < 8; ++c) {   // merge the 4 sub-waves
      acc[c] += __shfl_xor(acc[c], 16);
      acc[c] += __shfl_xor(acc[c], 32);
    }
    uint4 us = g4[n * 16 + q];       // self-loop (dinv folded in g)
    ACC8(us);
    float p0 = 0.f, p1 = 0.f;
    #pragma unroll
    for (int c = 0; c < 8; ++c) {
      float y = fmaxf(fmaf(acc[c], d, bb[c]), 0.f);
      p0 = fmaf(y, wj0[c], p0);
      p1 = fmaf(y, wj1[c], p1);
    }
    #pragma unroll
    for (int off = 1; off < 16; off <<= 1) {
      p0 += __shfl_xor(p0, off);
      p1 += __shfl_xor(p1, off);
    }
    if (q == 0) g2w[n * 4 + sub] = pack_bf16x2(d * p0, d * p1);
  }
}

// ---------- propagate-2: 4 threads/node (edge-split pairs), 8-deep ILP ----------
__global__ __launch_bounds__(256) void prop2_k(const uint2* __restrict__ g2v,
    const int* __restrict__ row_ptr, const unsigned short* __restrict__ csr,
    const float* __restrict__ dinv, const float* __restrict__ bout,
    float* __restrict__ out, int N) {
  int tid = blockIdx.x * 256 + threadIdx.x;
  int n = tid >> 2;
  if (n >= N) return;
  int hf = tid & 1, part = (tid >> 1) & 1;
  int start = row_ptr[n], end = row_ptr[n + 1];
  int mid = start + ((end - start) >> 1);
  int e  = part ? mid : start;
  int e1 = part ? end : mid;
  float a0 = 0.f, a1 = 0.f, a2 = 0.f, a3 = 0.f;
  if (!part) {
    uint2 us = g2v[n * 2 + hf];     // self-loop
    a0 = bf_lo(us.x); a1 = bf_hi(us.x);
    a2 = bf_lo(us.y); a3 = bf_hi(us.y);
  }
  for (; e + 8 <= e1; e += 8) {
    int i0 = csr[e],     i1 = csr[e + 1], i2 = csr[e + 2], i3 = csr[e + 3];
    int i4 = csr[e + 4], i5 = csr[e + 5], i6 = csr[e + 6], i7 = csr[e + 7];
    uint2 u0 = g2v[i0 * 2 + hf], u1 = g2v[i1 * 2 + hf];
    uint2 u2 = g2v[i2 * 2 + hf], u3 = g2v[i3 * 2 + hf];
    uint2 u4 = g2v[i4 * 2 + hf], u5 = g2v[i5 * 2 + hf];
    uint2 u6 = g2v[i6 * 2 + hf], u7 = g2v[i7 * 2 + hf];
    a0 += ((bf_lo(u0.x) + bf_lo(u1.x)) + (bf_lo(u2.x) + bf_lo(u3.x)))
        + ((bf_lo(u4.x) + bf_lo(u5.x)) + (bf_lo(u6.x) + bf_lo(u7.x)));
    a1 += ((bf_hi(u0.x) + bf_hi(u1.x)) + (bf_hi(u2.x) + bf_hi(u3.x)))
        + ((bf_hi(u4.x) + bf_hi(u5.x)) + (bf_hi(u6.x) + bf_hi(u7.x)));
    a2 += ((bf_lo(u0.y) + bf_lo(u1.y)) + (bf_lo(u2.y) + bf_lo(u3.y)))
        + ((bf_lo(u4.y) + bf_lo(u5.y)) + (bf_lo(u6.y) + bf_lo(u7.y)));
    a3 += ((bf_hi(u0.y) + bf_hi(u1.y)) + (bf_hi(u2.y) + bf_hi(u3.y)))
        + ((bf_hi(u4.y) + bf_hi(u5.y)) + (bf_hi(u6.y) + bf_hi(u7.y)));
  }
  for (; e + 4 <= e1; e += 4) {
    int i0 = csr[e], i1 = csr[e + 1], i2 = csr[e + 2], i3 = csr[e + 3];
    uint2 u0 = g2v[i0 * 2 + hf], u1 = g2v[i1 * 2 + hf];
    uint2 u2 = g2v[i2 * 2 + hf], u3 = g2v[i3 * 2 + hf];
    a0 += (bf_lo(u0.x) + bf_lo(u1.x)) + (bf_lo(u2.x) + bf_lo(u3.x));
    a1 += (bf_hi(u0.x) + bf_hi(u1.x)) + (bf_hi(u2.x) + bf_hi(u3.x));
    a2 += (bf_lo(u0.y) + bf_lo(u1.y)) + (bf_lo(u2.y) + bf_lo(u3.y));
    a3 += (bf_hi(u0.y) + bf_hi(u1.y)) + (bf_hi(u2.y) + bf_hi(u3.y));
  }
  for (; e < e1; ++e) {
    uint2 u = g2v[csr[e] * 2 + hf];
    a0 += bf_lo(u.x); a1 += bf_hi(u.x);
    a2 += bf_lo(u.y); a3 += bf_hi(u.y);
  }
  // combine the two edge-halves (partner thread = tid^2, same wave)
  a0 += __shfl_xor(a0, 2);
  a1 += __shfl_xor(a1, 2);
  a2 += __shfl_xor(a2, 2);
  a3 += __shfl_xor(a3, 2);
  if (!part) {
    float d = dinv[n];
    float2 o0 = make_float2(fmaf(d, a0, bout[hf * 4 + 0]), fmaf(d, a1, bout[hf * 4 + 1]));
    float2 o1 = make_float2(fmaf(d, a2, bout[hf * 4 + 2]), fmaf(d, a3, bout[hf * 4 + 3]));
    *(float2*)&out[(size_t)(hf * 2 + 0) * (2 * N) + 2 * n] = o0;
    *(float2*)&out[(size_t)(hf * 2 + 1) * (2 * N) + 2 * n] = o1;
  }
}

extern "C" void kernel_launch(void* const* d_in, const int* in_sizes, int n_in,
                              void* d_out, int out_size, void* d_ws, size_t ws_size,
                              hipStream_t stream) {
  const float* x    = (const float*)d_in[0];
  const int*   ei   = (const int*)d_in[1];
  const float* W1   = (const float*)d_in[2];
  const float* b1   = (const float*)d_in[3];
  const float* Wout = (const float*)d_in[4];
  const float* bout = (const float*)d_in[5];
  float* out = (float*)d_out;

  const int N = in_sizes[0] / CIN;       // 50000
  const int E = in_sizes[1] / 2;         // 1600000
  const int* srcp = ei;
  const int* dstp = ei + E;
  const int NSB = (N + 255) >> SSHIFT;   // 196 super-buckets
  const int NSC = NSB * NBLKB;           // 50176 scan entries

  char* ws = (char*)d_ws;
  size_t off = 0;
  auto alloc = [&](size_t bytes) -> void* {
    void* p = ws + off;
    off = (off + bytes + 511) & ~(size_t)511;
    return p;
  };
  unsigned*       gu        = (unsigned*)alloc((size_t)N * 64 * 4);      // bf16 g, row-major
  unsigned short* g2u       = (unsigned short*)alloc((size_t)N * 8 * 2); // bf16 g2
  float*          dinv      = (float*)alloc((size_t)N * 4);
  int*            blockhist = (int*)alloc((size_t)NSC * 4);
  int*            soff      = (int*)alloc((size_t)NSC * 4);
  int*            btot      = (int*)alloc(256 * 4);
  int*            row_ptr   = (int*)alloc((size_t)(N + 1) * 4);
  unsigned short* csr       = (unsigned short*)alloc((size_t)E * 2);
  unsigned*       stage     = (unsigned*)alloc((size_t)E * 4);
  (void)ws_size; (void)n_in; (void)out_size;

  histsb_k<<<NBLKB, 256, 0, stream>>>(dstp, blockhist, E, NSB);
  scan_k<<<NSB, 256, 0, stream>>>(blockhist, soff, btot, NSC);
  stageB_k<<<NBLKB, 256, 0, stream>>>(srcp, dstp, soff, btot, stage, E, NSB);
  csrsb_k<<<NSB, 256, 0, stream>>>(stage, btot, row_ptr, csr, dinv, N, E, NSB);

  gemm_k<<<(N + 127) / 128, 256, 0, stream>>>(x, W1, dinv, gu, N);

  const int P1_BLOCKS = 2048;
  prop1_k<<<P1_BLOCKS, 256, 0, stream>>>((const uint4*)gu, row_ptr, csr, dinv, b1,
                                         Wout, (unsigned*)g2u, N, P1_BLOCKS * 4);
  prop2_k<<<(4 * N + 255) / 256, 256, 0, stream>>>((const uint2*)g2u, row_ptr, csr,
                                                   dinv, bout, out, N);
}